// Round 7
// baseline (3225.190 us; speedup 1.0000x reference)
//
#include <hip/hip_runtime.h>

typedef unsigned short u16;
typedef unsigned int   u32;
typedef __bf16 bf16x8 __attribute__((ext_vector_type(8)));
typedef float  f32x4  __attribute__((ext_vector_type(4)));
typedef u32    u32x2  __attribute__((ext_vector_type(2)));

#define DIMD  256
#define DIMH  512
#define NTHREADS 512

// LDS (u16 units). Row strides padded +16B (keeps b128 alignment).
// Two independent 32-row sub-problems A and B, each with its own u/h tile.
#define USTR 264
#define HSTR 520
#define U_A 0
#define U_B (32*USTR)              // 8448
#define H_A (64*USTR)              // 16896
#define H_B (H_A + 32*HSTR)        // 33536
#define LDS_U16 (H_A + 64*HSTR)    // 50176 u16 = 100352 B

#define DT 0.0625f

__device__ __forceinline__ u16 f2bf(float f) {          // RNE fp32->bf16
  u32 u = __float_as_uint(f);
  u += 0x7FFFu + ((u >> 16) & 1u);
  return (u16)(u >> 16);
}
__device__ __forceinline__ u32 pk(float a, float b) {
#if __has_builtin(__builtin_amdgcn_cvt_pk_bf16_f32)
  auto v = __builtin_amdgcn_cvt_pk_bf16_f32(a, b);      // v_cvt_pk_bf16_f32 (RNE)
  u32 r; __builtin_memcpy(&r, &v, 4); return r;
#else
  return (u32)f2bf(a) | ((u32)f2bf(b) << 16);
#endif
}
__device__ __forceinline__ float bflo(u32 p) { return __uint_as_float(p << 16); }
__device__ __forceinline__ float bfhi(u32 p) { return __uint_as_float(p & 0xFFFF0000u); }
__device__ __forceinline__ float tanh_fast(float x) {
  float e = __builtin_amdgcn_exp2f(x * 2.8853900817779268f);  // 2*log2(e)
  return 1.0f - 2.0f * __builtin_amdgcn_rcpf(e + 1.0f);
}

// Barrier that drains ONLY LDS ops (lgkmcnt); in-flight global weight
// prefetches survive. 0xC07F = vmcnt(63) expcnt(7) lgkmcnt(0).
__device__ __forceinline__ void bar_lds() {
  asm volatile("" ::: "memory");
  __builtin_amdgcn_s_waitcnt(0xC07F);
  __builtin_amdgcn_s_barrier();
  asm volatile("" ::: "memory");
}

// W1[256][512] -> W1T bf16 [hcol=512][k=256]; W2[512][256] -> W2T bf16 [dcol=256][k=512]
__global__ void convert_w(const float* __restrict__ W1, const float* __restrict__ W2,
                          u16* __restrict__ w1t, u16* __restrict__ w2t) {
  int idx = blockIdx.x * 256 + threadIdx.x;
  {
    int n = idx >> 8, k = idx & 255;
    w1t[idx] = f2bf(W1[k * DIMH + n]);
  }
  {
    int n = idx >> 9, k = idx & 511;
    w2t[idx] = f2bf(W2[k * DIMD + n]);
  }
}

__device__ __forceinline__ void mfma_g1(f32x4 (&acc)[4][2],
                                        const bf16x8 (&a)[4], const bf16x8 (&b)[2]) {
#pragma unroll
  for (int mb = 0; mb < 4; ++mb)
#pragma unroll
    for (int nb = 0; nb < 2; ++nb)
      acc[mb][nb] = __builtin_amdgcn_mfma_f32_16x16x32_bf16(a[mb], b[nb], acc[mb][nb], 0, 0, 0);
}
__device__ __forceinline__ void mfma_g2(f32x4 (&acc)[2][2],
                                        const bf16x8 (&a)[2], const bf16x8 (&b)[2]) {
#pragma unroll
  for (int mb = 0; mb < 2; ++mb)
#pragma unroll
    for (int nb = 0; nb < 2; ++nb)
      acc[mb][nb] = __builtin_amdgcn_mfma_f32_16x16x32_bf16(a[mb], b[nb], acc[mb][nb], 0, 0, 0);
}

// Dual-pipeline: two independent 32-row sub-problems (A, B) phase-shifted by
// half a stage. Each barrier region interleaves X.GEMM1 with Y.GEMM2 (two
// independent dep-chains inside one wave) so ds_read/vmcnt waits of one chain
// hide under the other's MFMAs. Per-thread state totals match the proven
// round-0 budget (yv 16+16, st 16+16, accs 48 concurrent, frags 80).
// Tripwire: FETCH must stay ~12.5MB (GBs => spilled => revert).
__global__ __attribute__((amdgpu_flat_work_group_size(NTHREADS, NTHREADS),
                          amdgpu_waves_per_eu(2, 2)))
void ode_fused(
    const float* __restrict__ x,   const float* __restrict__ b1,
    const float* __restrict__ b2,  const float* __restrict__ wfc,
    const float* __restrict__ bfc, const u16* __restrict__ w1t,
    const u16* __restrict__ w2t,   float* __restrict__ out)
{
  __shared__ u16 lds[LDS_U16];
  __shared__ u32 k2f[16 * NTHREADS];     // parked k2: A at [0,8*N), B at [8*N,16*N)

  const int tid   = threadIdx.x;
  const int wg    = blockIdx.x;
  const int wv    = tid >> 6;          // wave 0..7
  const int lane  = tid & 63;
  const int lanel = lane & 15;
  const int laneq = lane >> 4;

  const u16* uRdA = &lds[U_A + lanel * USTR + laneq * 8];
  const u16* uRdB = &lds[U_B + lanel * USTR + laneq * 8];
  const u16* hRdA = &lds[H_A + lanel * HSTR + laneq * 8];
  const u16* hRdB = &lds[H_B + lanel * HSTR + laneq * 8];
  u16* uWrA = &lds[U_A + lanel * USTR + wv * 32 + laneq * 4];
  u16* uWrB = &lds[U_B + lanel * USTR + wv * 32 + laneq * 4];
  u16* hWrA = &lds[H_A + lanel * HSTR + wv * 64 + laneq * 4];
  u16* hWrB = &lds[H_B + lanel * HSTR + wv * 64 + laneq * 4];
  u32* k2fA = k2f;
  u32* k2fB = k2f + 8 * NTHREADS;

  // Per-sub-problem thread ownership (its GEMM2 C/D fragment):
  //   rows:  nb*16 + lanel               (nb 0..1)  [+32 for B]
  //   dcols: wv*32 + mb*16 + laneq*4 + r (mb 0..1, r 0..3)
  // flat i = nb*8 + mb*4 + r ; packed pair p = nb*4 + mb*2 + (r>>1)  (p 0..7)

  u32 b1p[8], b2p[4];
#pragma unroll
  for (int mb = 0; mb < 4; ++mb) {
    int base = wv * 64 + mb * 16 + laneq * 4;
    b1p[mb * 2 + 0] = pk(b1[base + 0], b1[base + 1]);
    b1p[mb * 2 + 1] = pk(b1[base + 2], b1[base + 3]);
  }
#pragma unroll
  for (int mb = 0; mb < 2; ++mb) {
    int base = wv * 32 + mb * 16 + laneq * 4;
    b2p[mb * 2 + 0] = pk(b2[base + 0], b2[base + 1]);
    b2p[mb * 2 + 1] = pk(b2[base + 2], b2[base + 3]);
  }

  float yvA[16], yvB[16];
  u32 stA[16], stB[16];     // [0:8) k1, [8:16) k3 (packed bf16 pairs)

  // x load + u1 write, both halves
#pragma unroll
  for (int half = 0; half < 2; ++half) {
    float* yv = half ? yvB : yvA;
    u16* uWr  = half ? uWrB : uWrA;
    int off   = half * 32;
#pragma unroll
    for (int nb = 0; nb < 2; ++nb)
#pragma unroll
      for (int mb = 0; mb < 2; ++mb) {
        const float4 v = *(const float4*)&x[(wg * 64 + off + nb * 16 + lanel) * DIMD +
                                            wv * 32 + mb * 16 + laneq * 4];
        int i = nb * 8 + mb * 4;
        yv[i + 0] = v.x; yv[i + 1] = v.y; yv[i + 2] = v.z; yv[i + 3] = v.w;
        u32x2 w; w.x = pk(v.x, v.y); w.y = pk(v.z, v.w);
        *(u32x2*)(uWr + nb * 16 * USTR + mb * 16) = w;
      }
  }

  const u16* w1base[4];
#pragma unroll
  for (int mb = 0; mb < 4; ++mb)
    w1base[mb] = w1t + (wv * 64 + mb * 16 + lanel) * DIMD + laneq * 8;
  const u16* w2base[2];
#pragma unroll
  for (int mb = 0; mb < 2; ++mb)
    w2base[mb] = w2t + (wv * 32 + mb * 16 + lanel) * DIMH + laneq * 8;

  auto ldW1 = [&](bf16x8 (&a)[4], int kk) {
#pragma unroll
    for (int mb = 0; mb < 4; ++mb) a[mb] = *(const bf16x8*)(w1base[mb] + kk * 32);
  };
  auto ldU = [&](bf16x8 (&b)[2], const u16* base, int kk) {
#pragma unroll
    for (int nb = 0; nb < 2; ++nb) b[nb] = *(const bf16x8*)(base + nb * 16 * USTR + kk * 32);
  };
  auto ldW2 = [&](bf16x8 (&a)[2], int kk) {
#pragma unroll
    for (int mb = 0; mb < 2; ++mb) a[mb] = *(const bf16x8*)(w2base[mb] + kk * 32);
  };
  auto ldH = [&](bf16x8 (&b)[2], const u16* base, int kk) {
#pragma unroll
    for (int nb = 0; nb < 2; ++nb) b[nb] = *(const bf16x8*)(base + nb * 16 * HSTR + kk * 32);
  };

  bf16x8 aP1[4], cP2[2];    // cross-barrier weight prefetch (W1 kk=0, W2 kk=0)

  // epi1: h = tanh(acc + b1) for sub-problem X
  auto epi1 = [&](f32x4 (&acc)[4][2], u16* hWrX) {
#pragma unroll
    for (int mb = 0; mb < 4; ++mb)
#pragma unroll
      for (int nb = 0; nb < 2; ++nb) {
        float h0 = tanh_fast(acc[mb][nb][0] + bflo(b1p[mb * 2 + 0]));
        float h1 = tanh_fast(acc[mb][nb][1] + bfhi(b1p[mb * 2 + 0]));
        float h2 = tanh_fast(acc[mb][nb][2] + bflo(b1p[mb * 2 + 1]));
        float h3 = tanh_fast(acc[mb][nb][3] + bfhi(b1p[mb * 2 + 1]));
        u32x2 w; w.x = pk(h0, h1); w.y = pk(h2, h3);
        *(u32x2*)(hWrX + nb * 16 * HSTR + mb * 16) = w;
      }
  };

  // ---------------- prologue: B.GEMM1(stage 1) ----------------
  {
    bf16x8 aA[4], aB[4], bA[2], bB[2];
    ldW1(aA, 0);
    bar_lds();              // u1A/u1B visible; weight prefetch in flight
    f32x4 acc[4][2];
#pragma unroll
    for (int mb = 0; mb < 4; ++mb)
#pragma unroll
      for (int nb = 0; nb < 2; ++nb) acc[mb][nb] = (f32x4){0.f, 0.f, 0.f, 0.f};
    ldU(bA, uRdB, 0);
#pragma unroll 1
    for (int kk2 = 0; kk2 < 3; ++kk2) {
      ldW1(aB, 2 * kk2 + 1); ldU(bB, uRdB, 2 * kk2 + 1);
      mfma_g1(acc, aA, bA);
      ldW1(aA, 2 * kk2 + 2); ldU(bA, uRdB, 2 * kk2 + 2);
      mfma_g1(acc, aB, bB);
    }
    ldW1(aB, 7); ldU(bB, uRdB, 7);
    mfma_g1(acc, aA, bA);
    ldW1(aP1, 0);           // blockA: A.GEMM1 weights
    mfma_g1(acc, aB, bB);
    epi1(acc, hWrB);
    ldW2(cP2, 0);           // blockA: B.GEMM2 weights
    bar_lds();              // hB visible; aP1/cP2 in flight
  }

  // ---------------- the block: X.GEMM1(s[+1]) interleaved with Y.GEMM2(s);
  //                  Y.epi2(s); X.epi1; barrier. ----------------
  auto block = [&](float (&yvY)[16], u32 (&stY)[16],
                   const u16* uRdX, u16* hWrX,
                   const u16* hRdY, u16* uWrY, u32* k2fY, int s) {
    f32x4 acc1[4][2], acc2[2][2];
#pragma unroll
    for (int mb = 0; mb < 4; ++mb)
#pragma unroll
      for (int nb = 0; nb < 2; ++nb) acc1[mb][nb] = (f32x4){0.f, 0.f, 0.f, 0.f};
#pragma unroll
    for (int mb = 0; mb < 2; ++mb)
#pragma unroll
      for (int nb = 0; nb < 2; ++nb) acc2[mb][nb] = (f32x4){0.f, 0.f, 0.f, 0.f};

    bf16x8 a1c[4], a1n[4], b1c[2], b1n[2];   // X.G1 frags (dbuf)
    bf16x8 c2c[2], c2n[2], d2c[2], d2n[2];   // Y.G2 frags (dbuf)
#pragma unroll
    for (int mb = 0; mb < 4; ++mb) a1c[mb] = aP1[mb];
#pragma unroll
    for (int mb = 0; mb < 2; ++mb) c2c[mb] = cP2[mb];
    ldU(b1c, uRdX, 0);
    ldH(d2c, hRdY, 0);

    // interleaved k-loop: G1 halfsteps 2k,2k+1 ; G2 halfsteps 4k..4k+3
#pragma unroll 1
    for (int k = 0; k < 3; ++k) {
      ldW1(a1n, 2 * k + 1); ldU(b1n, uRdX, 2 * k + 1);
      ldW2(c2n, 4 * k + 1); ldH(d2n, hRdY, 4 * k + 1);
      mfma_g2(acc2, c2c, d2c);                        // q=4k
      mfma_g1(acc1, a1c, b1c);                        // h=2k
      ldW1(a1c, 2 * k + 2); ldU(b1c, uRdX, 2 * k + 2);
      ldW2(c2c, 4 * k + 2); ldH(d2c, hRdY, 4 * k + 2);
      mfma_g2(acc2, c2n, d2n);                        // q=4k+1
      mfma_g1(acc1, a1n, b1n);                        // h=2k+1
      ldW2(c2n, 4 * k + 3); ldH(d2n, hRdY, 4 * k + 3);
      mfma_g2(acc2, c2c, d2c);                        // q=4k+2
      ldW2(c2c, 4 * k + 4); ldH(d2c, hRdY, 4 * k + 4);
      mfma_g2(acc2, c2n, d2n);                        // q=4k+3
    }
    // tail k=3: halfsteps h=6,7 ; q=12..15 + next-block weight prefetch
    ldW1(a1n, 7); ldU(b1n, uRdX, 7);
    ldW2(c2n, 13); ldH(d2n, hRdY, 13);
    mfma_g2(acc2, c2c, d2c);                          // q=12
    mfma_g1(acc1, a1c, b1c);                          // h=6
    ldW2(c2c, 14); ldH(d2c, hRdY, 14);
    ldW1(aP1, 0);                                     // next block X'.G1
    mfma_g2(acc2, c2n, d2n);                          // q=13
    mfma_g1(acc1, a1n, b1n);                          // h=7
    ldW2(c2n, 15); ldH(d2n, hRdY, 15);
    mfma_g2(acc2, c2c, d2c);                          // q=14
    ldW2(cP2, 0);                                     // next block Y'.G2
    mfma_g2(acc2, c2n, d2n);                          // q=15

    // ---------- Y.epi2(s): k_s = acc2 + b2; update yvY/stY/uY ----------
    if (s == 1) {
      const float C = DT * 0.2f;
#pragma unroll
      for (int mb = 0; mb < 2; ++mb)
#pragma unroll
        for (int nb = 0; nb < 2; ++nb) {
          int i = nb * 8 + mb * 4, p = nb * 4 + mb * 2;
          float k0 = acc2[mb][nb][0] + bflo(b2p[mb * 2 + 0]);
          float k1 = acc2[mb][nb][1] + bfhi(b2p[mb * 2 + 0]);
          float k2 = acc2[mb][nb][2] + bflo(b2p[mb * 2 + 1]);
          float k3 = acc2[mb][nb][3] + bfhi(b2p[mb * 2 + 1]);
          stY[p] = pk(k0, k1); stY[p + 1] = pk(k2, k3);
          u32x2 w;
          w.x = pk(yvY[i] + C * k0, yvY[i + 1] + C * k1);
          w.y = pk(yvY[i + 2] + C * k2, yvY[i + 3] + C * k3);
          *(u32x2*)(uWrY + nb * 16 * USTR + mb * 16) = w;
        }
    } else if (s == 2) {
      const float C1 = DT * 0.075f, C2 = DT * 0.225f;
#pragma unroll
      for (int mb = 0; mb < 2; ++mb)
#pragma unroll
        for (int nb = 0; nb < 2; ++nb) {
          int i = nb * 8 + mb * 4, p = nb * 4 + mb * 2;
          float k0 = acc2[mb][nb][0] + bflo(b2p[mb * 2 + 0]);
          float k1 = acc2[mb][nb][1] + bfhi(b2p[mb * 2 + 0]);
          float k2 = acc2[mb][nb][2] + bflo(b2p[mb * 2 + 1]);
          float k3 = acc2[mb][nb][3] + bfhi(b2p[mb * 2 + 1]);
          k2fY[p * NTHREADS + tid]       = pk(k0, k1);
          k2fY[(p + 1) * NTHREADS + tid] = pk(k2, k3);
          u32x2 w;
          w.x = pk(yvY[i]     + C1 * bflo(stY[p])     + C2 * k0,
                   yvY[i + 1] + C1 * bfhi(stY[p])     + C2 * k1);
          w.y = pk(yvY[i + 2] + C1 * bflo(stY[p + 1]) + C2 * k2,
                   yvY[i + 3] + C1 * bfhi(stY[p + 1]) + C2 * k3);
          *(u32x2*)(uWrY + nb * 16 * USTR + mb * 16) = w;
        }
    } else if (s == 3) {
      const float C1 = DT * (float)(44.0/45.0);
      const float C2 = DT * (float)(-56.0/15.0);
      const float C3 = DT * (float)(32.0/9.0);
#pragma unroll
      for (int mb = 0; mb < 2; ++mb)
#pragma unroll
        for (int nb = 0; nb < 2; ++nb) {
          int i = nb * 8 + mb * 4, p = nb * 4 + mb * 2;
          float k0 = acc2[mb][nb][0] + bflo(b2p[mb * 2 + 0]);
          float k1 = acc2[mb][nb][1] + bfhi(b2p[mb * 2 + 0]);
          float k2 = acc2[mb][nb][2] + bflo(b2p[mb * 2 + 1]);
          float k3 = acc2[mb][nb][3] + bfhi(b2p[mb * 2 + 1]);
          stY[8 + p] = pk(k0, k1); stY[8 + p + 1] = pk(k2, k3);
          u32 q0 = k2fY[p * NTHREADS + tid], q1 = k2fY[(p + 1) * NTHREADS + tid];
          u32x2 w;
          w.x = pk(yvY[i]     + C1 * bflo(stY[p])     + C2 * bflo(q0) + C3 * k0,
                   yvY[i + 1] + C1 * bfhi(stY[p])     + C2 * bfhi(q0) + C3 * k1);
          w.y = pk(yvY[i + 2] + C1 * bflo(stY[p + 1]) + C2 * bflo(q1) + C3 * k2,
                   yvY[i + 3] + C1 * bfhi(stY[p + 1]) + C2 * bfhi(q1) + C3 * k3);
          *(u32x2*)(uWrY + nb * 16 * USTR + mb * 16) = w;
        }
    } else if (s == 4) {
      const float C51 = DT * (float)(19372.0/6561.0);
      const float C52 = DT * (float)(-25360.0/2187.0);
      const float C53 = DT * (float)(64448.0/6561.0);
      const float C54 = DT * (float)(-212.0/729.0);
      const float D61 = DT * (float)(9017.0/3168.0  - 35.0/384.0);
      const float D62 = DT * (float)(-355.0/33.0);
      const float D63 = DT * (float)(46732.0/5247.0 - 500.0/1113.0);
      const float D64 = DT * (float)(49.0/176.0     - 125.0/192.0);
      const float E1  = DT * (float)(35.0/384.0);
      const float E3  = DT * (float)(500.0/1113.0);
      const float E4  = DT * (float)(125.0/192.0);
#pragma unroll
      for (int mb = 0; mb < 2; ++mb)
#pragma unroll
        for (int nb = 0; nb < 2; ++nb) {
          int i = nb * 8 + mb * 4, p = nb * 4 + mb * 2;
          float k40 = acc2[mb][nb][0] + bflo(b2p[mb * 2 + 0]);
          float k41 = acc2[mb][nb][1] + bfhi(b2p[mb * 2 + 0]);
          float k42 = acc2[mb][nb][2] + bflo(b2p[mb * 2 + 1]);
          float k43 = acc2[mb][nb][3] + bfhi(b2p[mb * 2 + 1]);
          float k10 = bflo(stY[p]),      k11 = bfhi(stY[p]);
          float k12 = bflo(stY[p + 1]),  k13 = bfhi(stY[p + 1]);
          u32 q0 = k2fY[p * NTHREADS + tid], q1 = k2fY[(p + 1) * NTHREADS + tid];
          float k20 = bflo(q0), k21 = bfhi(q0);
          float k22 = bflo(q1), k23 = bfhi(q1);
          float k30 = bflo(stY[8 + p]),     k31 = bfhi(stY[8 + p]);
          float k32 = bflo(stY[8 + p + 1]), k33 = bfhi(stY[8 + p + 1]);
          u32x2 w;
          w.x = pk(yvY[i]     + C51 * k10 + C52 * k20 + C53 * k30 + C54 * k40,
                   yvY[i + 1] + C51 * k11 + C52 * k21 + C53 * k31 + C54 * k41);
          w.y = pk(yvY[i + 2] + C51 * k12 + C52 * k22 + C53 * k32 + C54 * k42,
                   yvY[i + 3] + C51 * k13 + C52 * k23 + C53 * k33 + C54 * k43);
          *(u32x2*)(uWrY + nb * 16 * USTR + mb * 16) = w;
          stY[p]     = pk(D61 * k10 + D62 * k20 + D63 * k30 + D64 * k40,
                          D61 * k11 + D62 * k21 + D63 * k31 + D64 * k41);
          stY[p + 1] = pk(D61 * k12 + D62 * k22 + D63 * k32 + D64 * k42,
                          D61 * k13 + D62 * k23 + D63 * k33 + D64 * k43);
          yvY[i]     += E1 * k10 + E3 * k30 + E4 * k40;
          yvY[i + 1] += E1 * k11 + E3 * k31 + E4 * k41;
          yvY[i + 2] += E1 * k12 + E3 * k32 + E4 * k42;
          yvY[i + 3] += E1 * k13 + E3 * k33 + E4 * k43;
        }
    } else if (s == 5) {
      const float D65 = DT * (float)(-5103.0/18656.0 + 2187.0/6784.0);
      const float E5  = DT * (float)(-2187.0/6784.0);
#pragma unroll
      for (int mb = 0; mb < 2; ++mb)
#pragma unroll
        for (int nb = 0; nb < 2; ++nb) {
          int i = nb * 8 + mb * 4, p = nb * 4 + mb * 2;
          float k0 = acc2[mb][nb][0] + bflo(b2p[mb * 2 + 0]);
          float k1 = acc2[mb][nb][1] + bfhi(b2p[mb * 2 + 0]);
          float k2 = acc2[mb][nb][2] + bflo(b2p[mb * 2 + 1]);
          float k3 = acc2[mb][nb][3] + bfhi(b2p[mb * 2 + 1]);
          u32x2 w;
          w.x = pk(yvY[i]     + bflo(stY[p])     + D65 * k0,
                   yvY[i + 1] + bfhi(stY[p])     + D65 * k1);
          w.y = pk(yvY[i + 2] + bflo(stY[p + 1]) + D65 * k2,
                   yvY[i + 3] + bfhi(stY[p + 1]) + D65 * k3);
          *(u32x2*)(uWrY + nb * 16 * USTR + mb * 16) = w;
          yvY[i]     += E5 * k0;
          yvY[i + 1] += E5 * k1;
          yvY[i + 2] += E5 * k2;
          yvY[i + 3] += E5 * k3;
        }
    } else {
      const float E6 = DT * (float)(11.0/84.0);
#pragma unroll
      for (int mb = 0; mb < 2; ++mb)
#pragma unroll
        for (int nb = 0; nb < 2; ++nb) {
          int i = nb * 8 + mb * 4;
          yvY[i]     += E6 * (acc2[mb][nb][0] + bflo(b2p[mb * 2 + 0]));
          yvY[i + 1] += E6 * (acc2[mb][nb][1] + bfhi(b2p[mb * 2 + 0]));
          yvY[i + 2] += E6 * (acc2[mb][nb][2] + bflo(b2p[mb * 2 + 1]));
          yvY[i + 3] += E6 * (acc2[mb][nb][3] + bfhi(b2p[mb * 2 + 1]));
          u32x2 w;
          w.x = pk(yvY[i], yvY[i + 1]); w.y = pk(yvY[i + 2], yvY[i + 3]);
          *(u32x2*)(uWrY + nb * 16 * USTR + mb * 16) = w;
        }
    }

    // ---------- X.epi1 ----------
    epi1(acc1, hWrX);
    bar_lds();
  };

  // steady state: per stage s, blockA then blockB.
#pragma unroll 1
  for (int step = 0; step < 16; ++step) {
#pragma unroll 1
    for (int s = 1; s <= 6; ++s) {
      // blockA: A.G1(s) || B.G2(s); B.epi2(s); A.epi1
      block(yvB, stB, uRdA, hWrA, hRdB, uWrB, k2fB, s);
      // blockB: B.G1(s+1) || A.G2(s); A.epi2(s); B.epi1
      // (at step=15,s=6 the B.G1 is a harmless dead computation)
      block(yvA, stA, uRdB, hWrB, hRdA, uWrA, k2fA, s);
    }
  }

  // ---- out[row] = y . Wfc + bfc ----
  {
    float wfcv[8];
#pragma unroll
    for (int mb = 0; mb < 2; ++mb)
#pragma unroll
      for (int r = 0; r < 4; ++r)
        wfcv[mb * 4 + r] = wfc[wv * 32 + mb * 16 + laneq * 4 + r];
    float* redf = (float*)lds;   // safe: last bar_lds drained all U/H readers
    float pr[4];
#pragma unroll
    for (int g = 0; g < 4; ++g) {
      const float* Y = (g < 2) ? yvA : yvB;
      float p = 0.f;
#pragma unroll
      for (int mb = 0; mb < 2; ++mb)
#pragma unroll
        for (int r = 0; r < 4; ++r)
          p += Y[(g & 1) * 8 + mb * 4 + r] * wfcv[mb * 4 + r];
      p += __shfl_xor(p, 16);
      p += __shfl_xor(p, 32);
      pr[g] = p;
    }
    if (laneq == 0) {
#pragma unroll
      for (int g = 0; g < 4; ++g)
        redf[(g * 16 + lanel) * 8 + wv] = pr[g];
    }
    __syncthreads();
    if (tid < 64) {
      float s = bfc[0];
#pragma unroll
      for (int w = 0; w < 8; ++w) s += redf[tid * 8 + w];
      out[wg * 64 + tid] = s;
    }
  }
}

extern "C" void kernel_launch(void* const* d_in, const int* in_sizes, int n_in,
                              void* d_out, int out_size, void* d_ws, size_t ws_size,
                              hipStream_t stream) {
  const float* x   = (const float*)d_in[0];
  const float* W1  = (const float*)d_in[1];
  const float* b1  = (const float*)d_in[2];
  const float* W2  = (const float*)d_in[3];
  const float* b2  = (const float*)d_in[4];
  const float* wfc = (const float*)d_in[5];
  const float* bfc = (const float*)d_in[6];
  float* out = (float*)d_out;

  u16* w1t = (u16*)d_ws;                 // [512][256] bf16
  u16* w2t = w1t + DIMH * DIMD;          // [256][512] bf16

  hipLaunchKernelGGL(convert_w, dim3(512), dim3(256), 0, stream, W1, W2, w1t, w2t);
  hipLaunchKernelGGL(ode_fused, dim3(16384 / 64), dim3(NTHREADS), 0, stream,
                     x, b1, b2, wfc, bfc, w1t, w2t, out);
}